// Round 13
// baseline (122.090 us; speedup 1.0000x reference)
//
#include <hip/hip_runtime.h>
#include <hip/hip_bf16.h>
#include <stdint.h>

// CAM: out = gamma * (A @ softmax(A^T A)) + x,  A = x.reshape(B, N, C)
// B=32, N=4096 (64*64), C=256.
// Pipeline (R11 structure, best measured 101.4us; R12 band-split and R10
// 1024-thr fusion both falsified — see journal):
//   K1: symmetric aTa, splitK=8; one WG per (b,ks) stages a 256c x 64n slab
//       per kt with coalesced row loads + in-lane transpose -> swizzled LDS;
//       tile is BOTH MFMA operands.  bf16 partials (32MB, nt stores)
//       -> d_out[64MB..96MB)
//   K2: reduce 8 bf16 partials (nt loads) + softmax + transpose -> attnT
//       (d_ws, 4MB).  256 blocks (1/CU), 32 c-rows each.
//   K3: out = gamma * (A @ attn) + x.  128x128 tile, 4 blocks/CU, nt stores.

typedef __attribute__((ext_vector_type(8))) short bf16x8s;
typedef __attribute__((ext_vector_type(8))) unsigned short u16x8;
typedef __attribute__((ext_vector_type(4))) unsigned short u16x4;
typedef __attribute__((ext_vector_type(4))) float f32x4;
typedef __attribute__((ext_vector_type(4))) float fl4;
typedef __attribute__((ext_vector_type(4))) uint32_t u32x4;

__device__ __forceinline__ unsigned short f2bf(float f) {
  union { float f; uint32_t u; } v; v.f = f;
  uint32_t r = v.u + 0x7FFFu + ((v.u >> 16) & 1u);
  return (unsigned short)(r >> 16);
}

__device__ __forceinline__ float bf2f(unsigned short h) {
  union { float f; uint32_t u; } v; v.u = ((uint32_t)h) << 16; return v.f;
}

// packed f32 pair -> 2x bf16 in one u32 (low = lo), RNE
__device__ __forceinline__ uint32_t cvtpk(float lo, float hi) {
  __hip_bfloat162 h = __float22bfloat162_rn(float2{lo, hi});
  union { __hip_bfloat162 h; uint32_t u; } v; v.h = h; return v.u;
}

__device__ __forceinline__ void gload16(const void* g, void* l) {
  __builtin_amdgcn_global_load_lds(
      (const __attribute__((address_space(1))) uint32_t*)g,
      (__attribute__((address_space(3))) uint32_t*)l, 16, 0, 0);
}

// ---------------------------------------------------------------- K1
// aTa[c,d] = sum_n x[n,c]*x[n,d] (symmetric): stage ONE 256c x 64n bf16 tile,
// use it as both A and B.  Per WG (512 thr, 8 waves): full 256x256 output,
// K-slab of 512 (splitK=8).  grid = 32*8 = 256; x read exactly once.
// Staging per kt: wave w, instr j: lane l loads fl4 at (row w*8+j, col 4l)
// -> 1KB fully-coalesced row per instruction; lane reg-transposes its 8n x 4c
// block, cvtpk -> 4x ds_write_b128 into XOR-swizzled LDS
// ([256 c][64 n] bf16, byte ^= (row&7)<<4) — zero bank conflicts (measured;
// the b64 variant of this pattern conflicts 16-way, see R10).
// T14: LOAD(kt+1)->MFMA->WRITE->bar.  Partials bf16 + nontemporal stores
// (write-once stream; keeps L2 for x).
__global__ __launch_bounds__(512, 2) void k1_ata(
    const float* __restrict__ x, unsigned short* __restrict__ part) {
  __shared__ __align__(16) unsigned short S[2][256 * 64];

  int bid = blockIdx.x;                 // 0..255
  int b = bid >> 3, ks = bid & 7;
  const float* xb = x + ((size_t)b << 20);
  const int nsl = ks * 512;

  int t = threadIdx.x, w = t >> 6, l = t & 63;
  int wm = w >> 1, wn = w & 1;          // 4x2 wave grid: 64-row x 128-col
  int fr = l & 15, fh = l >> 4;

  f32x4 acc[4][8];
#pragma unroll
  for (int m = 0; m < 4; ++m)
#pragma unroll
    for (int n = 0; n < 8; ++n) acc[m][n] = (f32x4)(0.0f);

  fl4 v[8];                             // rows w*8+j, cols [4l,4l+4)
  auto LOAD = [&](int kt) {
    const float* s0 = xb + (size_t)(nsl + kt * 64 + w * 8) * 256 + 4 * l;
#pragma unroll
    for (int j = 0; j < 8; ++j) v[j] = *(const fl4*)&s0[(size_t)j * 256];
  };
  auto WRITE = [&](int bsel) {
#pragma unroll
    for (int i = 0; i < 4; ++i) {
      int c = 4 * l + i;
      uint32_t w0 = cvtpk(v[0][i], v[1][i]);
      uint32_t w1 = cvtpk(v[2][i], v[3][i]);
      uint32_t w2 = cvtpk(v[4][i], v[5][i]);
      uint32_t w3 = cvtpk(v[6][i], v[7][i]);
      int byt = c * 128 + ((w * 16) ^ ((c & 7) << 4));
      *(u32x4*)&S[bsel][byt >> 1] = u32x4{w0, w1, w2, w3};
    }
  };

  LOAD(0);
  WRITE(0);
  __syncthreads();

#pragma unroll 1
  for (int kt = 0; kt < 8; ++kt) {
    if (kt < 7) LOAD(kt + 1);
    const unsigned short* Sb = S[kt & 1];
#pragma unroll
    for (int h = 0; h < 2; ++h) {
      bf16x8s afr[4], bfr[8];
#pragma unroll
      for (int m = 0; m < 4; ++m) {
        int row = wm * 64 + m * 16 + fr;
        int byt = row * 128 + ((h * 64 + fh * 16) ^ ((row & 7) << 4));
        afr[m] = *(const bf16x8s*)&Sb[byt >> 1];
      }
#pragma unroll
      for (int n = 0; n < 8; ++n) {
        int row = wn * 128 + n * 16 + fr;
        int byt = row * 128 + ((h * 64 + fh * 16) ^ ((row & 7) << 4));
        bfr[n] = *(const bf16x8s*)&Sb[byt >> 1];
      }
#pragma unroll
      for (int m = 0; m < 4; ++m)
#pragma unroll
        for (int n = 0; n < 8; ++n)
          acc[m][n] = __builtin_amdgcn_mfma_f32_16x16x32_bf16(
              afr[m], bfr[n], acc[m][n], 0, 0, 0);
    }
    if (kt < 7) WRITE((kt + 1) & 1);
    __syncthreads();
  }

  unsigned short* pb = part + ((size_t)bid << 16);  // bid = b*8+ks, 128KB bf16
#pragma unroll
  for (int m = 0; m < 4; ++m) {
    int row = wm * 64 + m * 16 + fh * 4;
#pragma unroll
    for (int n = 0; n < 8; ++n) {
      int col = wn * 128 + n * 16 + fr;
#pragma unroll
      for (int i = 0; i < 4; ++i)
        __builtin_nontemporal_store(f2bf(acc[m][n][i]),
                                    &pb[(size_t)(row + i) * 256 + col]);
    }
  }
}

// ---------------------------------------------------------------- K2
// sum 8 bf16 split-K partials, softmax over d, write attnT[b][d][c] (bf16).
// grid = 32*8 = 256 blocks (32 c-rows each, 1 WG/CU), 256 threads (4 waves).
// Lane l owns cols 4l..4l+3 -> u16x4 contiguous loads (512B/wave/instr),
// nontemporal (read-once stream).
// LDS transpose [256 d][34 c] (odd stride, conflict-light); output segments
// 32 c x 2B = 64B aligned.
__global__ __launch_bounds__(256) void k2_softmax(
    const unsigned short* __restrict__ part, unsigned short* __restrict__ attnT) {
  __shared__ unsigned short T[256][34];
  int d = blockIdx.x;
  int b = d >> 3, cblk = d & 7;
  int t = threadIdx.x, w = t >> 6, l = t & 63;
  const unsigned short* pb =
      part + ((size_t)(b * 8) << 16) + (size_t)(cblk * 32) * 256 + 4 * l;

#pragma unroll 2
  for (int it = 0; it < 8; ++it) {
    int c = w * 8 + it;                    // local row 0..31
    float s[4] = {0.f, 0.f, 0.f, 0.f};
#pragma unroll
    for (int k = 0; k < 8; ++k) {
      u16x4 vv = __builtin_nontemporal_load(
          (const u16x4*)&pb[((size_t)k << 16) + (size_t)c * 256]);
#pragma unroll
      for (int i = 0; i < 4; ++i) s[i] += bf2f(vv[i]);
    }
    float mx = fmaxf(fmaxf(s[0], s[1]), fmaxf(s[2], s[3]));
    for (int off = 32; off; off >>= 1) mx = fmaxf(mx, __shfl_xor(mx, off));
    float sum = 0.0f;
#pragma unroll
    for (int i = 0; i < 4; ++i) { s[i] = __expf(s[i] - mx); sum += s[i]; }
    for (int off = 32; off; off >>= 1) sum += __shfl_xor(sum, off);
    float inv = 1.0f / sum;
#pragma unroll
    for (int i = 0; i < 4; ++i) T[4 * l + i][c] = f2bf(s[i] * inv);
  }
  __syncthreads();

  unsigned short* ab = attnT + ((size_t)b << 16) + (size_t)t * 256 + cblk * 32;
#pragma unroll
  for (int c8 = 0; c8 < 4; ++c8) {
    u16x8 vv;
#pragma unroll
    for (int j = 0; j < 8; ++j) vv[j] = T[t][c8 * 8 + j];
    *(u16x8*)&ab[c8 * 8] = vv;
  }
}

// ---------------------------------------------------------------- K3
// out[n,d] = gamma * sum_c x[n,c]*attn[c,d] + x[n,d].
// Per WG: 128n x 128d, K=256 in 8 steps of 32.  grid = 32*64 = 2048,
// 256 threads (4 waves, 2x2), acc[4][4] -> 4 blocks/CU.
// A: reg-staged f32->bf16 into swizzled LDS [128][32];
// B: global_load_lds from attnT into swizzled LDS [128][32].
// XCD-swizzled; out stored non-temporally (write-once).
__global__ __launch_bounds__(256, 4) void k3_av(
    const float* __restrict__ x, const unsigned short* __restrict__ attnT,
    const float* __restrict__ gamma, float* __restrict__ out) {
  __shared__ __align__(16) unsigned short A_s[2][128 * 32];
  __shared__ __align__(16) unsigned short B_s[2][128 * 32];

  int dd = blockIdx.x;
  int xcd = dd & 7, slot = dd >> 3;        // slot 0..255
  int b = xcd + 8 * (slot >> 6);           // 4 batches per XCD
  int inner = slot & 63;
  int mt = inner >> 1, dt = inner & 1;     // n-tile 0..31, d-tile 0..1
  int n0 = mt << 7, d0 = dt << 7;
  const float* xb = x + ((size_t)b << 20);
  const unsigned short* ab = attnT + ((size_t)b << 16);
  float* ob = out + ((size_t)b << 20);

  int t = threadIdx.x, w = t >> 6, l = t & 63;
  int wm = w >> 1, wn = w & 1;
  int fr = l & 15, fh = l >> 4;

  int ar = t >> 1, ah = t & 1;             // A staging: row, half
  const float* aSrc = xb + (size_t)(n0 + ar) * 256 + ah * 16;
  int brow = l >> 2;                       // B staging: row in 16-row segment
  int bhi = (l & 3) ^ (brow & 3);          // pre-swizzled 16B slot

  f32x4 acc[4][4];
#pragma unroll
  for (int m = 0; m < 4; ++m)
#pragma unroll
    for (int n = 0; n < 4; ++n) acc[m][n] = (f32x4)(0.0f);

  auto STAGE_A = [&](int bsel, int k0) {
    uint32_t pk[8];
#pragma unroll
    for (int q = 0; q < 4; ++q) {
      fl4 vv = *(const fl4*)&aSrc[k0 + q * 4];
      pk[2 * q]     = cvtpk(vv.x, vv.y);
      pk[2 * q + 1] = cvtpk(vv.z, vv.w);
    }
#pragma unroll
    for (int j = 0; j < 2; ++j) {
      int hi = ah * 2 + j;
      int byt = ar * 64 + ((hi ^ (ar & 3)) << 4);
      *(u32x4*)&A_s[bsel][byt >> 1] =
          u32x4{pk[4 * j], pk[4 * j + 1], pk[4 * j + 2], pk[4 * j + 3]};
    }
  };

  auto STAGE_B = [&](int bsel, int k0) {
#pragma unroll
    for (int r = 0; r < 2; ++r) {
      int seg = r * 4 + w;                 // 8 segments of 16 rows
      int row = d0 + seg * 16 + brow;
      gload16(&ab[(size_t)row * 256 + k0 + bhi * 8], &B_s[bsel][seg * 512]);
    }
  };

  STAGE_A(0, 0);
  STAGE_B(0, 0);
  __syncthreads();

  int buf = 0;
#pragma unroll 1
  for (int kt = 0; kt < 8; ++kt) {
    if (kt < 7) { STAGE_A(buf ^ 1, (kt + 1) * 32); STAGE_B(buf ^ 1, (kt + 1) * 32); }
    bf16x8s af[4];
#pragma unroll
    for (int m = 0; m < 4; ++m) {
      int row = wm * 64 + m * 16 + fr;
      int byt = row * 64 + ((fh ^ (row & 3)) << 4);
      af[m] = *(const bf16x8s*)&A_s[buf][byt >> 1];
    }
    bf16x8s bfv[4];
#pragma unroll
    for (int n = 0; n < 4; ++n) {
      int dn = wn * 64 + n * 16 + fr;
      int byt = dn * 64 + ((fh ^ (dn & 3)) << 4);
      bfv[n] = *(const bf16x8s*)&B_s[buf][byt >> 1];
    }
#pragma unroll
    for (int m = 0; m < 4; ++m)
#pragma unroll
      for (int n = 0; n < 4; ++n)
        acc[m][n] = __builtin_amdgcn_mfma_f32_16x16x32_bf16(
            af[m], bfv[n], acc[m][n], 0, 0, 0);
    __syncthreads();
    buf ^= 1;
  }

  float g = gamma[0];
#pragma unroll
  for (int m = 0; m < 4; ++m) {
    int row = wm * 64 + m * 16 + fh * 4;
#pragma unroll
    for (int n = 0; n < 4; ++n) {
      int col = d0 + wn * 64 + n * 16 + fr;
#pragma unroll
      for (int i = 0; i < 4; ++i) {
        size_t idx = (size_t)(n0 + row + i) * 256 + col;
        __builtin_nontemporal_store(g * acc[m][n][i] + xb[idx], &ob[idx]);
      }
    }
  }
}

// ---------------------------------------------------------------- launch
extern "C" void kernel_launch(void* const* d_in, const int* in_sizes, int n_in,
                              void* d_out, int out_size, void* d_ws, size_t ws_size,
                              hipStream_t stream) {
  const float* x     = (const float*)d_in[0];
  const float* gamma = (const float*)d_in[1];
  float* out = (float*)d_out;

  // scratch layout: bf16 partials (32MB) live in d_out[64MB..96MB) (dead
  // before K3 rewrites it); attnT (4MB) in d_ws (K3 reads it while writing
  // d_out).
  unsigned short* part  = (unsigned short*)((char*)d_out + (size_t)64 * 1024 * 1024);
  unsigned short* attnT = (unsigned short*)d_ws;

  k1_ata<<<256, 512, 0, stream>>>(x, part);
  k2_softmax<<<256, 256, 0, stream>>>(part, attnT);
  k3_av<<<2048, 256, 0, stream>>>(x, attnT, gamma, out);
}

// Round 14
// 101.176 us; speedup vs baseline: 1.2067x; 1.2067x over previous
//
#include <hip/hip_runtime.h>
#include <hip/hip_bf16.h>
#include <stdint.h>

// CAM: out = gamma * (A @ softmax(A^T A)) + x,  A = x.reshape(B, N, C)
// B=32, N=4096 (64*64), C=256.
// R14 = exact revert to R11 (best measured: 101.4us).  Falsified variants:
//   R6/R12 band-split K1 (duplicated staging work on the critical path),
//   R10 fused softmax (132KB LDS -> 1 WG/CU + b64-write bank conflicts),
//   R13 nt partial stores (broke store merging: VGPR 88->112, LDS conflicts).
// Pipeline:
//   K1: symmetric aTa, splitK=8; one WG per (b,ks) stages a 256c x 64n slab
//       per kt with coalesced row loads + in-lane transpose -> swizzled LDS;
//       tile is BOTH MFMA operands.  bf16 partials (32MB) -> d_out[64MB..96MB)
//   K2: reduce 8 bf16 partials + softmax + transpose -> attnT bf16 (d_ws, 4MB)
//       256 blocks (1/CU), 32 c-rows each.
//   K3: out = gamma * (A @ attn) + x.  128x128 tile, 4 blocks/CU, nt stores.

typedef __attribute__((ext_vector_type(8))) short bf16x8s;
typedef __attribute__((ext_vector_type(8))) unsigned short u16x8;
typedef __attribute__((ext_vector_type(4))) unsigned short u16x4;
typedef __attribute__((ext_vector_type(4))) float f32x4;
typedef __attribute__((ext_vector_type(4))) float fl4;
typedef __attribute__((ext_vector_type(4))) uint32_t u32x4;

__device__ __forceinline__ unsigned short f2bf(float f) {
  union { float f; uint32_t u; } v; v.f = f;
  uint32_t r = v.u + 0x7FFFu + ((v.u >> 16) & 1u);
  return (unsigned short)(r >> 16);
}

__device__ __forceinline__ float bf2f(unsigned short h) {
  union { float f; uint32_t u; } v; v.u = ((uint32_t)h) << 16; return v.f;
}

// packed f32 pair -> 2x bf16 in one u32 (low = lo), RNE
__device__ __forceinline__ uint32_t cvtpk(float lo, float hi) {
  __hip_bfloat162 h = __float22bfloat162_rn(float2{lo, hi});
  union { __hip_bfloat162 h; uint32_t u; } v; v.h = h; return v.u;
}

__device__ __forceinline__ void gload16(const void* g, void* l) {
  __builtin_amdgcn_global_load_lds(
      (const __attribute__((address_space(1))) uint32_t*)g,
      (__attribute__((address_space(3))) uint32_t*)l, 16, 0, 0);
}

// ---------------------------------------------------------------- K1
// aTa[c,d] = sum_n x[n,c]*x[n,d] (symmetric): stage ONE 256c x 64n bf16 tile,
// use it as both A and B.  Per WG (512 thr, 8 waves): full 256x256 output,
// K-slab of 512 (splitK=8).  grid = 32*8 = 256; x read exactly once.
// Staging per kt: wave w, instr j: lane l loads fl4 at (row w*8+j, col 4l)
// -> 1KB fully-coalesced row per instruction; lane reg-transposes its 8n x 4c
// block, cvtpk -> 4x ds_write_b128 into XOR-swizzled LDS
// ([256 c][64 n] bf16, byte ^= (row&7)<<4) — zero bank conflicts (measured).
// T14: LOAD(kt+1)->MFMA->WRITE->bar.
// Partials stored BF16 via plain merged stores (nt variant falsified, R13).
__global__ __launch_bounds__(512, 2) void k1_ata(
    const float* __restrict__ x, unsigned short* __restrict__ part) {
  __shared__ __align__(16) unsigned short S[2][256 * 64];

  int bid = blockIdx.x;                 // 0..255
  int b = bid >> 3, ks = bid & 7;
  const float* xb = x + ((size_t)b << 20);
  const int nsl = ks * 512;

  int t = threadIdx.x, w = t >> 6, l = t & 63;
  int wm = w >> 1, wn = w & 1;          // 4x2 wave grid: 64-row x 128-col
  int fr = l & 15, fh = l >> 4;

  f32x4 acc[4][8];
#pragma unroll
  for (int m = 0; m < 4; ++m)
#pragma unroll
    for (int n = 0; n < 8; ++n) acc[m][n] = (f32x4)(0.0f);

  fl4 v[8];                             // rows w*8+j, cols [4l,4l+4)
  auto LOAD = [&](int kt) {
    const float* s0 = xb + (size_t)(nsl + kt * 64 + w * 8) * 256 + 4 * l;
#pragma unroll
    for (int j = 0; j < 8; ++j) v[j] = *(const fl4*)&s0[(size_t)j * 256];
  };
  auto WRITE = [&](int bsel) {
#pragma unroll
    for (int i = 0; i < 4; ++i) {
      int c = 4 * l + i;
      uint32_t w0 = cvtpk(v[0][i], v[1][i]);
      uint32_t w1 = cvtpk(v[2][i], v[3][i]);
      uint32_t w2 = cvtpk(v[4][i], v[5][i]);
      uint32_t w3 = cvtpk(v[6][i], v[7][i]);
      int byt = c * 128 + ((w * 16) ^ ((c & 7) << 4));
      *(u32x4*)&S[bsel][byt >> 1] = u32x4{w0, w1, w2, w3};
    }
  };

  LOAD(0);
  WRITE(0);
  __syncthreads();

#pragma unroll 1
  for (int kt = 0; kt < 8; ++kt) {
    if (kt < 7) LOAD(kt + 1);
    const unsigned short* Sb = S[kt & 1];
#pragma unroll
    for (int h = 0; h < 2; ++h) {
      bf16x8s afr[4], bfr[8];
#pragma unroll
      for (int m = 0; m < 4; ++m) {
        int row = wm * 64 + m * 16 + fr;
        int byt = row * 128 + ((h * 64 + fh * 16) ^ ((row & 7) << 4));
        afr[m] = *(const bf16x8s*)&Sb[byt >> 1];
      }
#pragma unroll
      for (int n = 0; n < 8; ++n) {
        int row = wn * 128 + n * 16 + fr;
        int byt = row * 128 + ((h * 64 + fh * 16) ^ ((row & 7) << 4));
        bfr[n] = *(const bf16x8s*)&Sb[byt >> 1];
      }
#pragma unroll
      for (int m = 0; m < 4; ++m)
#pragma unroll
        for (int n = 0; n < 8; ++n)
          acc[m][n] = __builtin_amdgcn_mfma_f32_16x16x32_bf16(
              afr[m], bfr[n], acc[m][n], 0, 0, 0);
    }
    if (kt < 7) WRITE((kt + 1) & 1);
    __syncthreads();
  }

  unsigned short* pb = part + ((size_t)bid << 16);  // bid = b*8+ks, 128KB bf16
#pragma unroll
  for (int m = 0; m < 4; ++m) {
    int row = wm * 64 + m * 16 + fh * 4;
#pragma unroll
    for (int n = 0; n < 8; ++n) {
      int col = wn * 128 + n * 16 + fr;
#pragma unroll
      for (int i = 0; i < 4; ++i)
        pb[(size_t)(row + i) * 256 + col] = f2bf(acc[m][n][i]);
    }
  }
}

// ---------------------------------------------------------------- K2
// sum 8 bf16 split-K partials, softmax over d, write attnT[b][d][c] (bf16).
// grid = 32*8 = 256 blocks (32 c-rows each, 1 WG/CU), 256 threads (4 waves).
// Lane l owns cols 4l..4l+3 -> u16x4 contiguous loads (512B/wave/instr).
// LDS transpose [256 d][34 c] (odd stride, conflict-light); output segments
// 32 c x 2B = 64B aligned.
__global__ __launch_bounds__(256) void k2_softmax(
    const unsigned short* __restrict__ part, unsigned short* __restrict__ attnT) {
  __shared__ unsigned short T[256][34];
  int d = blockIdx.x;
  int b = d >> 3, cblk = d & 7;
  int t = threadIdx.x, w = t >> 6, l = t & 63;
  const unsigned short* pb =
      part + ((size_t)(b * 8) << 16) + (size_t)(cblk * 32) * 256 + 4 * l;

#pragma unroll 2
  for (int it = 0; it < 8; ++it) {
    int c = w * 8 + it;                    // local row 0..31
    float s[4] = {0.f, 0.f, 0.f, 0.f};
#pragma unroll
    for (int k = 0; k < 8; ++k) {
      u16x4 vv = *(const u16x4*)&pb[((size_t)k << 16) + (size_t)c * 256];
#pragma unroll
      for (int i = 0; i < 4; ++i) s[i] += bf2f(vv[i]);
    }
    float mx = fmaxf(fmaxf(s[0], s[1]), fmaxf(s[2], s[3]));
    for (int off = 32; off; off >>= 1) mx = fmaxf(mx, __shfl_xor(mx, off));
    float sum = 0.0f;
#pragma unroll
    for (int i = 0; i < 4; ++i) { s[i] = __expf(s[i] - mx); sum += s[i]; }
    for (int off = 32; off; off >>= 1) sum += __shfl_xor(sum, off);
    float inv = 1.0f / sum;
#pragma unroll
    for (int i = 0; i < 4; ++i) T[4 * l + i][c] = f2bf(s[i] * inv);
  }
  __syncthreads();

  unsigned short* ab = attnT + ((size_t)b << 16) + (size_t)t * 256 + cblk * 32;
#pragma unroll
  for (int c8 = 0; c8 < 4; ++c8) {
    u16x8 vv;
#pragma unroll
    for (int j = 0; j < 8; ++j) vv[j] = T[t][c8 * 8 + j];
    *(u16x8*)&ab[c8 * 8] = vv;
  }
}

// ---------------------------------------------------------------- K3
// out[n,d] = gamma * sum_c x[n,c]*attn[c,d] + x[n,d].
// Per WG: 128n x 128d, K=256 in 8 steps of 32.  grid = 32*64 = 2048,
// 256 threads (4 waves, 2x2), acc[4][4] -> 4 blocks/CU.
// A: reg-staged f32->bf16 into swizzled LDS [128][32];
// B: global_load_lds from attnT into swizzled LDS [128][32].
// XCD-swizzled; out stored non-temporally (vectorized f32 stores — benign).
__global__ __launch_bounds__(256, 4) void k3_av(
    const float* __restrict__ x, const unsigned short* __restrict__ attnT,
    const float* __restrict__ gamma, float* __restrict__ out) {
  __shared__ __align__(16) unsigned short A_s[2][128 * 32];
  __shared__ __align__(16) unsigned short B_s[2][128 * 32];

  int dd = blockIdx.x;
  int xcd = dd & 7, slot = dd >> 3;        // slot 0..255
  int b = xcd + 8 * (slot >> 6);           // 4 batches per XCD
  int inner = slot & 63;
  int mt = inner >> 1, dt = inner & 1;     // n-tile 0..31, d-tile 0..1
  int n0 = mt << 7, d0 = dt << 7;
  const float* xb = x + ((size_t)b << 20);
  const unsigned short* ab = attnT + ((size_t)b << 16);
  float* ob = out + ((size_t)b << 20);

  int t = threadIdx.x, w = t >> 6, l = t & 63;
  int wm = w >> 1, wn = w & 1;
  int fr = l & 15, fh = l >> 4;

  int ar = t >> 1, ah = t & 1;             // A staging: row, half
  const float* aSrc = xb + (size_t)(n0 + ar) * 256 + ah * 16;
  int brow = l >> 2;                       // B staging: row in 16-row segment
  int bhi = (l & 3) ^ (brow & 3);          // pre-swizzled 16B slot

  f32x4 acc[4][4];
#pragma unroll
  for (int m = 0; m < 4; ++m)
#pragma unroll
    for (int n = 0; n < 4; ++n) acc[m][n] = (f32x4)(0.0f);

  auto STAGE_A = [&](int bsel, int k0) {
    uint32_t pk[8];
#pragma unroll
    for (int q = 0; q < 4; ++q) {
      fl4 vv = *(const fl4*)&aSrc[k0 + q * 4];
      pk[2 * q]     = cvtpk(vv.x, vv.y);
      pk[2 * q + 1] = cvtpk(vv.z, vv.w);
    }
#pragma unroll
    for (int j = 0; j < 2; ++j) {
      int hi = ah * 2 + j;
      int byt = ar * 64 + ((hi ^ (ar & 3)) << 4);
      *(u32x4*)&A_s[bsel][byt >> 1] =
          u32x4{pk[4 * j], pk[4 * j + 1], pk[4 * j + 2], pk[4 * j + 3]};
    }
  };

  auto STAGE_B = [&](int bsel, int k0) {
#pragma unroll
    for (int r = 0; r < 2; ++r) {
      int seg = r * 4 + w;                 // 8 segments of 16 rows
      int row = d0 + seg * 16 + brow;
      gload16(&ab[(size_t)row * 256 + k0 + bhi * 8], &B_s[bsel][seg * 512]);
    }
  };

  STAGE_A(0, 0);
  STAGE_B(0, 0);
  __syncthreads();

  int buf = 0;
#pragma unroll 1
  for (int kt = 0; kt < 8; ++kt) {
    if (kt < 7) { STAGE_A(buf ^ 1, (kt + 1) * 32); STAGE_B(buf ^ 1, (kt + 1) * 32); }
    bf16x8s af[4];
#pragma unroll
    for (int m = 0; m < 4; ++m) {
      int row = wm * 64 + m * 16 + fr;
      int byt = row * 64 + ((fh ^ (row & 3)) << 4);
      af[m] = *(const bf16x8s*)&A_s[buf][byt >> 1];
    }
    bf16x8s bfv[4];
#pragma unroll
    for (int n = 0; n < 4; ++n) {
      int dn = wn * 64 + n * 16 + fr;
      int byt = dn * 64 + ((fh ^ (dn & 3)) << 4);
      bfv[n] = *(const bf16x8s*)&B_s[buf][byt >> 1];
    }
#pragma unroll
    for (int m = 0; m < 4; ++m)
#pragma unroll
      for (int n = 0; n < 4; ++n)
        acc[m][n] = __builtin_amdgcn_mfma_f32_16x16x32_bf16(
            af[m], bfv[n], acc[m][n], 0, 0, 0);
    __syncthreads();
    buf ^= 1;
  }

  float g = gamma[0];
#pragma unroll
  for (int m = 0; m < 4; ++m) {
    int row = wm * 64 + m * 16 + fh * 4;
#pragma unroll
    for (int n = 0; n < 4; ++n) {
      int col = d0 + wn * 64 + n * 16 + fr;
#pragma unroll
      for (int i = 0; i < 4; ++i) {
        size_t idx = (size_t)(n0 + row + i) * 256 + col;
        __builtin_nontemporal_store(g * acc[m][n][i] + xb[idx], &ob[idx]);
      }
    }
  }
}

// ---------------------------------------------------------------- launch
extern "C" void kernel_launch(void* const* d_in, const int* in_sizes, int n_in,
                              void* d_out, int out_size, void* d_ws, size_t ws_size,
                              hipStream_t stream) {
  const float* x     = (const float*)d_in[0];
  const float* gamma = (const float*)d_in[1];
  float* out = (float*)d_out;

  // scratch layout: bf16 partials (32MB) live in d_out[64MB..96MB) (dead
  // before K3 rewrites it); attnT (4MB) in d_ws (K3 reads it while writing
  // d_out).
  unsigned short* part  = (unsigned short*)((char*)d_out + (size_t)64 * 1024 * 1024);
  unsigned short* attnT = (unsigned short*)d_ws;

  k1_ata<<<256, 512, 0, stream>>>(x, part);
  k2_softmax<<<256, 256, 0, stream>>>(part, attnT);
  k3_av<<<2048, 256, 0, stream>>>(x, attnT, gamma, out);
}